// Round 10
// baseline (114.753 us; speedup 1.0000x reference)
//
#include <hip/hip_runtime.h>
#include <math.h>

namespace {

constexpr int B = 8;
constexpr int N = 8192;
constexpr int D = 1024;
constexpr int E = 4;
constexpr int BN = B * N;

__device__ __forceinline__ unsigned int orderkey(float p) {
    return __float_as_uint(p) | 0x80000000u;  // positive floats
}

// f64 exp, |x| <= ~8: ln2 hi/lo range reduction + degree-12 Taylor.
__device__ __forceinline__ double fast_exp64(double x) {
    const double L2E    = 1.4426950408889634074;
    const double LN2_HI = 6.93147180369123816490e-01;
    const double LN2_LO = 1.90821492927058770002e-10;
    const double nd = rint(x * L2E);
    double r = fma(-nd, LN2_HI, x);
    r = fma(-nd, LN2_LO, r);
    double p = 1.0 / 479001600.0;
    p = fma(p, r, 1.0 / 39916800.0);
    p = fma(p, r, 1.0 / 3628800.0);
    p = fma(p, r, 1.0 / 362880.0);
    p = fma(p, r, 1.0 / 40320.0);
    p = fma(p, r, 1.0 / 5040.0);
    p = fma(p, r, 1.0 / 720.0);
    p = fma(p, r, 1.0 / 120.0);
    p = fma(p, r, 1.0 / 24.0);
    p = fma(p, r, 1.0 / 6.0);
    p = fma(p, r, 0.5);
    p = fma(p, r, 1.0);
    p = fma(p, r, 1.0);
    const long long sc = ((long long)(1023 + (int)nd)) << 52;
    return p * __longlong_as_double(sc);
}

// ---------------------------------------------------------------------------
// DIAGNOSTIC probe: pure x-read at K1's exact grid/block/token mapping, no
// compute coupling (no LDS/shuffle/barrier). probe_time = dur_R10 - dur_R9.
// Sink: per-lane f32 accumulator kept live via asm (no DCE), plus one
// transient store per wave into probs_t[wave] -- K1 runs after and fully
// overwrites probs_t, so the final output is unchanged.
// ---------------------------------------------------------------------------
__global__ __launch_bounds__(256) void bw_probe_kernel(
    const float* __restrict__ x,   // [BN, D]
    float* __restrict__ probs_t)   // scratch sink (overwritten by K1)
{
    const int lane = threadIdx.x & 63;
    const int wv = threadIdx.x >> 6;
    const int tok0 = blockIdx.x * 64 + wv * 16;
    const float4* x4 = reinterpret_cast<const float4*>(x);

    float acc = 0.0f;
    for (int k = 0; k < 16; ++k) {
        const float4* xv = x4 + (size_t)(tok0 + k) * (D / 4);
        const float4 c0 = xv[lane];
        const float4 c1 = xv[lane + 64];
        const float4 c2 = xv[lane + 128];
        const float4 c3 = xv[lane + 192];
        acc += c0.x + c0.y + c0.z + c0.w;
        acc += c1.x + c1.y + c1.z + c1.w;
        acc += c2.x + c2.y + c2.z + c2.w;
        acc += c3.x + c3.y + c3.z + c3.w;
    }
    asm volatile("" :: "v"(acc));  // keep every load live (rule #17)
    if (lane == 0) probs_t[blockIdx.x * 4 + wv] = acc;  // transient
}

// ---------------------------------------------------------------------------
// Kernel 1: UNCHANGED from verified R9 (f64 W in LDS, 2 tokens/iter).
// ---------------------------------------------------------------------------
__global__ __launch_bounds__(256) void probs_kernel(
    const float* __restrict__ x,     // [BN, D]
    const float* __restrict__ W,     // [E, D]
    const float* __restrict__ bias,  // [E]
    float* __restrict__ probs_t)     // [B, E, N]
{
    __shared__ double2 s_WA[E][D / 4];  // 16 KB
    __shared__ double2 s_WB[E][D / 4];  // 16 KB
    __shared__ double s_l[64][4];       // 2 KB

    {
        const float4* W4 = reinterpret_cast<const float4*>(W);
        for (int i = threadIdx.x; i < E * D / 4; i += 256) {
            const int e = i >> 8, q = i & 255;
            const float4 w = W4[i];
            s_WA[e][q] = make_double2((double)w.x, (double)w.y);
            s_WB[e][q] = make_double2((double)w.z, (double)w.w);
        }
    }
    __syncthreads();

    const int lane = threadIdx.x & 63;
    const int wv = threadIdx.x >> 6;
    const int tok0 = blockIdx.x * 64 + wv * 16;
    const int j = ((lane & 1) << 1) | ((lane >> 1) & 1);

    const float4* x4 = reinterpret_cast<const float4*>(x);

    for (int k8 = 0; k8 < 8; ++k8) {
        const int tA = tok0 + 2 * k8;
        const float4* xvA = x4 + (size_t)tA * (D / 4);
        const float4* xvB = xvA + (D / 4);
        const float4 cA0 = xvA[lane];
        const float4 cA1 = xvA[lane + 64];
        const float4 cA2 = xvA[lane + 128];
        const float4 cA3 = xvA[lane + 192];
        const float4 cB0 = xvB[lane];
        const float4 cB1 = xvB[lane + 64];
        const float4 cB2 = xvB[lane + 128];
        const float4 cB3 = xvB[lane + 192];

        double a0 = 0.0, a1 = 0.0, a2 = 0.0, a3 = 0.0;
        double b0 = 0.0, b1 = 0.0, b2 = 0.0, b3 = 0.0;
#define CHUNK(XA, XB, CI)                                                      \
        {                                                                      \
            const int idx = lane + 64 * (CI);                                  \
            const double Ax = (double)(XA).x, Ay = (double)(XA).y;             \
            const double Az = (double)(XA).z, Aw = (double)(XA).w;             \
            const double Bx = (double)(XB).x, By = (double)(XB).y;             \
            const double Bz = (double)(XB).z, Bw = (double)(XB).w;             \
            {                                                                  \
                const double2 wA = s_WA[0][idx], wB = s_WB[0][idx];            \
                a0 = fma(Ax, wA.x, a0); a0 = fma(Ay, wA.y, a0);                \
                a0 = fma(Az, wB.x, a0); a0 = fma(Aw, wB.y, a0);                \
                b0 = fma(Bx, wA.x, b0); b0 = fma(By, wA.y, b0);                \
                b0 = fma(Bz, wB.x, b0); b0 = fma(Bw, wB.y, b0);                \
            }                                                                  \
            {                                                                  \
                const double2 wA = s_WA[1][idx], wB = s_WB[1][idx];            \
                a1 = fma(Ax, wA.x, a1); a1 = fma(Ay, wA.y, a1);                \
                a1 = fma(Az, wB.x, a1); a1 = fma(Aw, wB.y, a1);                \
                b1 = fma(Bx, wA.x, b1); b1 = fma(By, wA.y, b1);                \
                b1 = fma(Bz, wB.x, b1); b1 = fma(Bw, wB.y, b1);                \
            }                                                                  \
            {                                                                  \
                const double2 wA = s_WA[2][idx], wB = s_WB[2][idx];            \
                a2 = fma(Ax, wA.x, a2); a2 = fma(Ay, wA.y, a2);                \
                a2 = fma(Az, wB.x, a2); a2 = fma(Aw, wB.y, a2);                \
                b2 = fma(Bx, wA.x, b2); b2 = fma(By, wA.y, b2);                \
                b2 = fma(Bz, wB.x, b2); b2 = fma(Bw, wB.y, b2);                \
            }                                                                  \
            {                                                                  \
                const double2 wA = s_WA[3][idx], wB = s_WB[3][idx];            \
                a3 = fma(Ax, wA.x, a3); a3 = fma(Ay, wA.y, a3);                \
                a3 = fma(Az, wB.x, a3); a3 = fma(Aw, wB.y, a3);                \
                b3 = fma(Bx, wA.x, b3); b3 = fma(By, wA.y, b3);                \
                b3 = fma(Bz, wB.x, b3); b3 = fma(Bw, wB.y, b3);                \
            }                                                                  \
        }
        CHUNK(cA0, cB0, 0) CHUNK(cA1, cB1, 1) CHUNK(cA2, cB2, 2) CHUNK(cA3, cB3, 3)
#undef CHUNK

        {
            const double vA = (lane & 1) ? a0 : a2;
            const double wA = (lane & 1) ? a1 : a3;
            const double vB = (lane & 1) ? b0 : b2;
            const double wB = (lane & 1) ? b1 : b3;
            const double svA = __shfl_xor(vA, 1, 64);
            const double swA = __shfl_xor(wA, 1, 64);
            const double svB = __shfl_xor(vB, 1, 64);
            const double swB = __shfl_xor(wB, 1, 64);
            const double sA0 = (lane & 1) ? (a2 + svA) : (a0 + svA);
            const double sA1 = (lane & 1) ? (a3 + swA) : (a1 + swA);
            const double sB0 = (lane & 1) ? (b2 + svB) : (b0 + svB);
            const double sB1 = (lane & 1) ? (b3 + swB) : (b1 + swB);
            const double ttA = (lane & 2) ? sA0 : sA1;
            const double ttB = (lane & 2) ? sB0 : sB1;
            const double stA = __shfl_xor(ttA, 2, 64);
            const double stB = __shfl_xor(ttB, 2, 64);
            double sA = (lane & 2) ? (sA1 + stA) : (sA0 + stA);
            double sB = (lane & 2) ? (sB1 + stB) : (sB0 + stB);
            sA += __shfl_xor(sA, 4, 64);
            sB += __shfl_xor(sB, 4, 64);
            sA += __shfl_xor(sA, 8, 64);
            sB += __shfl_xor(sB, 8, 64);
            sA += __shfl_xor(sA, 16, 64);
            sB += __shfl_xor(sB, 16, 64);
            sA += __shfl_xor(sA, 32, 64);
            sB += __shfl_xor(sB, 32, 64);
            if (lane < 4) {
                s_l[wv * 16 + 2 * k8][j] = sA;
                s_l[wv * 16 + 2 * k8 + 1][j] = sB;
            }
        }
    }
    __syncthreads();

    {
        const int tok = threadIdx.x >> 2;
        const int e = threadIdx.x & 3;
        const double l0 = s_l[tok][0] + (double)bias[0];
        const double l1 = s_l[tok][1] + (double)bias[1];
        const double l2 = s_l[tok][2] + (double)bias[2];
        const double l3 = s_l[tok][3] + (double)bias[3];
        const double m = fmax(fmax(l0, l1), fmax(l2, l3));
        const double le = (e == 0) ? l0 : (e == 1) ? l1 : (e == 2) ? l2 : l3;
        const double ex = fast_exp64(le - m);
        double Z = ex + __shfl_xor(ex, 1, 64);
        Z += __shfl_xor(Z, 2, 64);
        const double p = ex / Z;
        const int token = blockIdx.x * 64 + tok;
        const int brow = token >> 13;
        const int n = token & (N - 1);
        probs_t[((size_t)brow * E + e) * N + n] = (float)p;
    }
}

// ---------------------------------------------------------------------------
// Kernel 2: routing (verified R6/R8/R9 version, verbatim).
// ---------------------------------------------------------------------------
__global__ __launch_bounds__(1024) void route_kernel(
    const float* __restrict__ probs_t,  // [B, E, N]
    float* __restrict__ out)            // [2*B*N]: mask (as float), then probs
{
    constexpr int TPB = 1024;
    constexpr int ITEMS = N / TPB;  // 8
    constexpr int NBKT = 4096;
    constexpr int CMAX = 64;

    __shared__ unsigned short s_bkt4[E][N];  // 64 KB
    __shared__ unsigned char s_exp[N];       // 8 KB
    __shared__ unsigned int s_hist[NBKT];    // 16 KB
    __shared__ unsigned int s_cand[CMAX];
    __shared__ unsigned int s_ckey[CMAX];
    __shared__ unsigned int s_wsum[32];
    __shared__ unsigned int s_sel[3];

    const int b = blockIdx.x;
    const int t = threadIdx.x;
    const int lane = t & 63;
    const int wv = t >> 6;

    for (int u = 0; u < ITEMS; ++u) s_exp[u * TPB + t] = 255;
#pragma unroll
    for (int e = 0; e < E; ++e) {
        const float* pe = probs_t + ((size_t)b * E + e) * N;
        for (int u = 0; u < ITEMS; ++u) {
            const int i = u * TPB + t;
            const float p = pe[i];
            int bk = (int)(p * 4096.0f);
            bk = bk > 4095 ? 4095 : (bk < 0 ? 0 : bk);
            s_bkt4[e][i] = (unsigned short)bk;
        }
    }

    const int kcap[E] = {819, 1228, 2048, 4096};
    int nun = N;

    for (int j = E - 1; j >= 0; --j) {
        const bool first = (j == E - 1);
        const int kk = min(kcap[j], nun);
        const float* pj = probs_t + ((size_t)b * E + j) * N;

        for (int u = 0; u < NBKT / TPB; ++u) s_hist[u * TPB + t] = 0;
        if (t == 0) s_sel[2] = 0;
        __syncthreads();

        for (int u = 0; u < ITEMS; ++u) {
            const int i = u * TPB + t;
            if (first || s_exp[i] == 255) atomicAdd(&s_hist[s_bkt4[j][i]], 1u);
        }
        __syncthreads();

        const unsigned int h0 = s_hist[4 * t], h1 = s_hist[4 * t + 1];
        const unsigned int h2 = s_hist[4 * t + 2], h3 = s_hist[4 * t + 3];
        const unsigned int lsum = h0 + h1 + h2 + h3;
        unsigned int sfx = lsum;
#pragma unroll
        for (int off = 1; off < 64; off <<= 1) {
            const unsigned int vv = __shfl_down(sfx, off, 64);
            if (lane + off < 64) sfx += vv;
        }
        if (lane == 0) s_wsum[wv] = sfx;
        __syncthreads();
        if (t < 16) {
            unsigned int acc = 0;
            for (int w2 = t + 1; w2 < 16; ++w2) acc += s_wsum[w2];
            s_wsum[16 + t] = acc;
        }
        __syncthreads();
        {
            unsigned int run = (sfx - lsum) + s_wsum[16 + wv];
            const unsigned int hh[4] = {h0, h1, h2, h3};
#pragma unroll
            for (int bi = 3; bi >= 0; --bi) {
                const unsigned int h = hh[bi];
                if (run < (unsigned)kk && run + h >= (unsigned)kk) {
                    s_sel[0] = (unsigned)(4 * t + bi);
                    s_sel[1] = (unsigned)kk - run;
                }
                run += h;
            }
        }
        __syncthreads();
        const int Bstar = (int)s_sel[0];
        const unsigned int rem = s_sel[1];

        for (int u = 0; u < ITEMS; ++u) {
            const int i = u * TPB + t;
            if (!first && s_exp[i] != 255) continue;
            const int bk = s_bkt4[j][i];
            if (bk > Bstar) {
                s_exp[i] = (unsigned char)j;
            } else if (bk == Bstar) {
                const unsigned int pos = atomicAdd(&s_sel[2], 1u);
                if (pos < CMAX) { s_cand[pos] = (unsigned int)i; s_ckey[pos] = orderkey(pj[i]); }
            }
        }
        __syncthreads();
        const unsigned int c = s_sel[2];

        if (rem == c) {
            for (int u = 0; u < ITEMS; ++u) {
                const int i = u * TPB + t;
                if ((first || s_exp[i] == 255) && s_bkt4[j][i] == Bstar)
                    s_exp[i] = (unsigned char)j;
            }
            __syncthreads();
        } else if (c <= CMAX) {
            if (wv == 0) {
                unsigned int key = 0u, idx = 0xFFFFFFFFu;
                if (lane < (int)c) { key = s_ckey[lane]; idx = s_cand[lane]; }
                unsigned long long v = ((unsigned long long)(~key) << 32) | idx;
                for (int k2 = 2; k2 <= 64; k2 <<= 1) {
                    for (int jj = k2 >> 1; jj >= 1; jj >>= 1) {
                        const unsigned long long pv = __shfl_xor(v, jj, 64);
                        const bool up = ((lane & k2) == 0);
                        const bool lower = ((lane & jj) == 0);
                        if (lower == up) v = (v < pv) ? v : pv;
                        else             v = (v > pv) ? v : pv;
                    }
                }
                if (lane < (int)rem) {
                    const unsigned int tok = (unsigned int)(v & 0xFFFFFFFFu);
                    s_exp[tok] = (unsigned char)j;
                }
            }
            __syncthreads();
        } else {
            unsigned int prefix = 0, remR = rem;
            for (int shift = 24; shift >= 0; shift -= 8) {
                if (t < 256) s_hist[t] = 0;
                __syncthreads();
                for (int u = 0; u < ITEMS; ++u) {
                    const int i = t * ITEMS + u;
                    if (s_exp[i] != 255) continue;
                    const unsigned int key = orderkey(pj[i]);
                    if (shift == 24 || (key >> (shift + 8)) == prefix)
                        atomicAdd(&s_hist[(key >> shift) & 255u], 1u);
                }
                __syncthreads();
                if (wv == 0) {
                    const unsigned int g0 = s_hist[4 * lane], g1 = s_hist[4 * lane + 1];
                    const unsigned int g2 = s_hist[4 * lane + 2], g3 = s_hist[4 * lane + 3];
                    const unsigned int ls = g0 + g1 + g2 + g3;
                    unsigned int sx = ls;
#pragma unroll
                    for (int off = 1; off < 64; off <<= 1) {
                        const unsigned int vv = __shfl_down(sx, off, 64);
                        if (lane + off < 64) sx += vv;
                    }
                    unsigned int rr = sx - ls;
                    const unsigned int gg[4] = {g0, g1, g2, g3};
#pragma unroll
                    for (int bi = 3; bi >= 0; --bi) {
                        const unsigned int h = gg[bi];
                        if (rr < remR && rr + h >= remR) {
                            s_sel[0] = (unsigned)(4 * lane + bi);
                            s_sel[1] = remR - rr;
                        }
                        rr += h;
                    }
                }
                __syncthreads();
                prefix = (prefix << 8) | s_sel[0];
                remR = s_sel[1];
            }
            const unsigned int T = prefix;
            unsigned int local = 0;
            for (int u = 0; u < ITEMS; ++u) {
                const int i = t * ITEMS + u;
                if (s_exp[i] == 255 && orderkey(pj[i]) == T) ++local;
            }
            unsigned int inc = local;
#pragma unroll
            for (int off = 1; off < 64; off <<= 1) {
                const unsigned int vv = __shfl_up(inc, off, 64);
                if (lane >= off) inc += vv;
            }
            if (lane == 63) s_wsum[wv] = inc;
            __syncthreads();
            if (t < 16) {
                unsigned int a2 = 0;
                for (int w2 = 0; w2 < t; ++w2) a2 += s_wsum[w2];
                s_wsum[16 + t] = a2;
            }
            __syncthreads();
            unsigned int taken = (inc - local) + s_wsum[16 + wv];
            for (int u = 0; u < ITEMS; ++u) {
                const int i = t * ITEMS + u;
                if (s_exp[i] != 255) continue;
                const unsigned int key = orderkey(pj[i]);
                if (key > T) {
                    s_exp[i] = (unsigned char)j;
                } else if (key == T) {
                    if (taken < remR) s_exp[i] = (unsigned char)j;
                    ++taken;
                }
            }
            __syncthreads();
        }
        nun -= kk;
    }

    float* out_mask = out;
    float* out_p = out + (size_t)BN;
    for (int u = 0; u < ITEMS; ++u) {
        const int i = u * TPB + t;
        int e = s_exp[i];
        if (e == 255) e = 0;
        out_mask[(size_t)b * N + i] = (float)e;
        out_p[(size_t)b * N + i] = probs_t[((size_t)b * E + e) * N + i];
    }
}

}  // namespace

extern "C" void kernel_launch(void* const* d_in, const int* in_sizes, int n_in,
                              void* d_out, int out_size, void* d_ws, size_t ws_size,
                              hipStream_t stream) {
    const float* x = (const float*)d_in[0];     // [B, N, D]
    const float* W = (const float*)d_in[1];     // [E, D]
    const float* bias = (const float*)d_in[2];  // [E]
    float* out = (float*)d_out;                 // [2*B*N] floats
    float* probs_t = (float*)d_ws;              // [B, E, N] fp32, 1 MB

    // DIAGNOSTIC (this round only): pure-read probe with K1's access pattern.
    // probe_time = dur_R10 - dur_R9. Its sink writes land in probs_t, which
    // probs_kernel fully overwrites -> final output unchanged.
    bw_probe_kernel<<<BN / 64, 256, 0, stream>>>(x, probs_t);
    probs_kernel<<<BN / 64, 256, 0, stream>>>(x, W, bias, probs_t);
    route_kernel<<<B, 1024, 0, stream>>>(probs_t, out);
}

// Round 11
// 71.011 us; speedup vs baseline: 1.6160x; 1.6160x over previous
//
#include <hip/hip_runtime.h>
#include <math.h>

namespace {

constexpr int B = 8;
constexpr int N = 8192;
constexpr int D = 1024;
constexpr int E = 4;
constexpr int BN = B * N;

__device__ __forceinline__ unsigned int orderkey(float p) {
    return __float_as_uint(p) | 0x80000000u;  // positive floats
}

// f64 exp, |x| <= ~8: ln2 hi/lo range reduction + degree-12 Taylor.
__device__ __forceinline__ double fast_exp64(double x) {
    const double L2E    = 1.4426950408889634074;
    const double LN2_HI = 6.93147180369123816490e-01;
    const double LN2_LO = 1.90821492927058770002e-10;
    const double nd = rint(x * L2E);
    double r = fma(-nd, LN2_HI, x);
    r = fma(-nd, LN2_LO, r);
    double p = 1.0 / 479001600.0;
    p = fma(p, r, 1.0 / 39916800.0);
    p = fma(p, r, 1.0 / 3628800.0);
    p = fma(p, r, 1.0 / 362880.0);
    p = fma(p, r, 1.0 / 40320.0);
    p = fma(p, r, 1.0 / 5040.0);
    p = fma(p, r, 1.0 / 720.0);
    p = fma(p, r, 1.0 / 120.0);
    p = fma(p, r, 1.0 / 24.0);
    p = fma(p, r, 1.0 / 6.0);
    p = fma(p, r, 0.5);
    p = fma(p, r, 1.0);
    p = fma(p, r, 1.0);
    const long long sc = ((long long)(1023 + (int)nd)) << 52;
    return p * __longlong_as_double(sc);
}

// ---------------------------------------------------------------------------
// Kernel 1: R9 structure (f64 W in LDS, 2 tokens/iter sharing W reads) PLUS
// software prefetch of the next 2-token group, so each wave keeps 8 KB of
// loads in flight during its ~1100-cyc compute phase (R10 probe proved the
// read path does 6.2 TB/s; R9's gap was zero-outstanding-loads dead time).
// No forced min-waves (R7 lesson). VGPR ~120 -> target 4 waves/SIMD.
// CHUNK/butterfly/softmax are byte-identical to verified R9 -> same output.
// ---------------------------------------------------------------------------
__global__ __launch_bounds__(256) void probs_kernel(
    const float* __restrict__ x,     // [BN, D]
    const float* __restrict__ W,     // [E, D]
    const float* __restrict__ bias,  // [E]
    float* __restrict__ probs_t)     // [B, E, N]
{
    __shared__ double2 s_WA[E][D / 4];  // 16 KB
    __shared__ double2 s_WB[E][D / 4];  // 16 KB
    __shared__ double s_l[64][4];       // 2 KB

    {
        const float4* W4 = reinterpret_cast<const float4*>(W);
        for (int i = threadIdx.x; i < E * D / 4; i += 256) {
            const int e = i >> 8, q = i & 255;
            const float4 w = W4[i];
            s_WA[e][q] = make_double2((double)w.x, (double)w.y);
            s_WB[e][q] = make_double2((double)w.z, (double)w.w);
        }
    }
    __syncthreads();

    const int lane = threadIdx.x & 63;
    const int wv = threadIdx.x >> 6;
    const int tok0 = blockIdx.x * 64 + wv * 16;
    const int j = ((lane & 1) << 1) | ((lane >> 1) & 1);

    const float4* x4 = reinterpret_cast<const float4*>(x);

    // preload group 0
    float4 cA0, cA1, cA2, cA3, cB0, cB1, cB2, cB3;
    {
        const float4* xvA = x4 + (size_t)tok0 * (D / 4);
        const float4* xvB = xvA + (D / 4);
        cA0 = xvA[lane]; cA1 = xvA[lane + 64];
        cA2 = xvA[lane + 128]; cA3 = xvA[lane + 192];
        cB0 = xvB[lane]; cB1 = xvB[lane + 64];
        cB2 = xvB[lane + 128]; cB3 = xvB[lane + 192];
    }

    for (int k8 = 0; k8 < 8; ++k8) {
        // issue next group's loads BEFORE compute (stay in flight under it)
        float4 nA0, nA1, nA2, nA3, nB0, nB1, nB2, nB3;
        if (k8 < 7) {
            const float4* xvA = x4 + (size_t)(tok0 + 2 * (k8 + 1)) * (D / 4);
            const float4* xvB = xvA + (D / 4);
            nA0 = xvA[lane]; nA1 = xvA[lane + 64];
            nA2 = xvA[lane + 128]; nA3 = xvA[lane + 192];
            nB0 = xvB[lane]; nB1 = xvB[lane + 64];
            nB2 = xvB[lane + 128]; nB3 = xvB[lane + 192];
        }

        double a0 = 0.0, a1 = 0.0, a2 = 0.0, a3 = 0.0;
        double b0 = 0.0, b1 = 0.0, b2 = 0.0, b3 = 0.0;
#define CHUNK(XA, XB, CI)                                                      \
        {                                                                      \
            const int idx = lane + 64 * (CI);                                  \
            const double Ax = (double)(XA).x, Ay = (double)(XA).y;             \
            const double Az = (double)(XA).z, Aw = (double)(XA).w;             \
            const double Bx = (double)(XB).x, By = (double)(XB).y;             \
            const double Bz = (double)(XB).z, Bw = (double)(XB).w;             \
            {                                                                  \
                const double2 wA = s_WA[0][idx], wB = s_WB[0][idx];            \
                a0 = fma(Ax, wA.x, a0); a0 = fma(Ay, wA.y, a0);                \
                a0 = fma(Az, wB.x, a0); a0 = fma(Aw, wB.y, a0);                \
                b0 = fma(Bx, wA.x, b0); b0 = fma(By, wA.y, b0);                \
                b0 = fma(Bz, wB.x, b0); b0 = fma(Bw, wB.y, b0);                \
            }                                                                  \
            {                                                                  \
                const double2 wA = s_WA[1][idx], wB = s_WB[1][idx];            \
                a1 = fma(Ax, wA.x, a1); a1 = fma(Ay, wA.y, a1);                \
                a1 = fma(Az, wB.x, a1); a1 = fma(Aw, wB.y, a1);                \
                b1 = fma(Bx, wA.x, b1); b1 = fma(By, wA.y, b1);                \
                b1 = fma(Bz, wB.x, b1); b1 = fma(Bw, wB.y, b1);                \
            }                                                                  \
            {                                                                  \
                const double2 wA = s_WA[2][idx], wB = s_WB[2][idx];            \
                a2 = fma(Ax, wA.x, a2); a2 = fma(Ay, wA.y, a2);                \
                a2 = fma(Az, wB.x, a2); a2 = fma(Aw, wB.y, a2);                \
                b2 = fma(Bx, wA.x, b2); b2 = fma(By, wA.y, b2);                \
                b2 = fma(Bz, wB.x, b2); b2 = fma(Bw, wB.y, b2);                \
            }                                                                  \
            {                                                                  \
                const double2 wA = s_WA[3][idx], wB = s_WB[3][idx];            \
                a3 = fma(Ax, wA.x, a3); a3 = fma(Ay, wA.y, a3);                \
                a3 = fma(Az, wB.x, a3); a3 = fma(Aw, wB.y, a3);                \
                b3 = fma(Bx, wA.x, b3); b3 = fma(By, wA.y, b3);                \
                b3 = fma(Bz, wB.x, b3); b3 = fma(Bw, wB.y, b3);                \
            }                                                                  \
        }
        CHUNK(cA0, cB0, 0) CHUNK(cA1, cB1, 1) CHUNK(cA2, cB2, 2) CHUNK(cA3, cB3, 3)
#undef CHUNK

        {
            const double vA = (lane & 1) ? a0 : a2;
            const double wA = (lane & 1) ? a1 : a3;
            const double vB = (lane & 1) ? b0 : b2;
            const double wB = (lane & 1) ? b1 : b3;
            const double svA = __shfl_xor(vA, 1, 64);
            const double swA = __shfl_xor(wA, 1, 64);
            const double svB = __shfl_xor(vB, 1, 64);
            const double swB = __shfl_xor(wB, 1, 64);
            const double sA0 = (lane & 1) ? (a2 + svA) : (a0 + svA);
            const double sA1 = (lane & 1) ? (a3 + swA) : (a1 + swA);
            const double sB0 = (lane & 1) ? (b2 + svB) : (b0 + svB);
            const double sB1 = (lane & 1) ? (b3 + swB) : (b1 + swB);
            const double ttA = (lane & 2) ? sA0 : sA1;
            const double ttB = (lane & 2) ? sB0 : sB1;
            const double stA = __shfl_xor(ttA, 2, 64);
            const double stB = __shfl_xor(ttB, 2, 64);
            double sA = (lane & 2) ? (sA1 + stA) : (sA0 + stA);
            double sB = (lane & 2) ? (sB1 + stB) : (sB0 + stB);
            sA += __shfl_xor(sA, 4, 64);
            sB += __shfl_xor(sB, 4, 64);
            sA += __shfl_xor(sA, 8, 64);
            sB += __shfl_xor(sB, 8, 64);
            sA += __shfl_xor(sA, 16, 64);
            sB += __shfl_xor(sB, 16, 64);
            sA += __shfl_xor(sA, 32, 64);
            sB += __shfl_xor(sB, 32, 64);
            if (lane < 4) {
                s_l[wv * 16 + 2 * k8][j] = sA;
                s_l[wv * 16 + 2 * k8 + 1][j] = sB;
            }
        }

        cA0 = nA0; cA1 = nA1; cA2 = nA2; cA3 = nA3;
        cB0 = nB0; cB1 = nB1; cB2 = nB2; cB3 = nB3;
    }
    __syncthreads();

    {
        const int tok = threadIdx.x >> 2;
        const int e = threadIdx.x & 3;
        const double l0 = s_l[tok][0] + (double)bias[0];
        const double l1 = s_l[tok][1] + (double)bias[1];
        const double l2 = s_l[tok][2] + (double)bias[2];
        const double l3 = s_l[tok][3] + (double)bias[3];
        const double m = fmax(fmax(l0, l1), fmax(l2, l3));
        const double le = (e == 0) ? l0 : (e == 1) ? l1 : (e == 2) ? l2 : l3;
        const double ex = fast_exp64(le - m);
        double Z = ex + __shfl_xor(ex, 1, 64);
        Z += __shfl_xor(Z, 2, 64);
        const double p = ex / Z;
        const int token = blockIdx.x * 64 + tok;
        const int brow = token >> 13;
        const int n = token & (N - 1);
        probs_t[((size_t)brow * E + e) * N + n] = (float)p;
    }
}

// ---------------------------------------------------------------------------
// Kernel 2: routing (verified R6/R8/R9 version, verbatim).
// ---------------------------------------------------------------------------
__global__ __launch_bounds__(1024) void route_kernel(
    const float* __restrict__ probs_t,  // [B, E, N]
    float* __restrict__ out)            // [2*B*N]: mask (as float), then probs
{
    constexpr int TPB = 1024;
    constexpr int ITEMS = N / TPB;  // 8
    constexpr int NBKT = 4096;
    constexpr int CMAX = 64;

    __shared__ unsigned short s_bkt4[E][N];  // 64 KB
    __shared__ unsigned char s_exp[N];       // 8 KB
    __shared__ unsigned int s_hist[NBKT];    // 16 KB
    __shared__ unsigned int s_cand[CMAX];
    __shared__ unsigned int s_ckey[CMAX];
    __shared__ unsigned int s_wsum[32];
    __shared__ unsigned int s_sel[3];

    const int b = blockIdx.x;
    const int t = threadIdx.x;
    const int lane = t & 63;
    const int wv = t >> 6;

    for (int u = 0; u < ITEMS; ++u) s_exp[u * TPB + t] = 255;
#pragma unroll
    for (int e = 0; e < E; ++e) {
        const float* pe = probs_t + ((size_t)b * E + e) * N;
        for (int u = 0; u < ITEMS; ++u) {
            const int i = u * TPB + t;
            const float p = pe[i];
            int bk = (int)(p * 4096.0f);
            bk = bk > 4095 ? 4095 : (bk < 0 ? 0 : bk);
            s_bkt4[e][i] = (unsigned short)bk;
        }
    }

    const int kcap[E] = {819, 1228, 2048, 4096};
    int nun = N;

    for (int j = E - 1; j >= 0; --j) {
        const bool first = (j == E - 1);
        const int kk = min(kcap[j], nun);
        const float* pj = probs_t + ((size_t)b * E + j) * N;

        for (int u = 0; u < NBKT / TPB; ++u) s_hist[u * TPB + t] = 0;
        if (t == 0) s_sel[2] = 0;
        __syncthreads();

        for (int u = 0; u < ITEMS; ++u) {
            const int i = u * TPB + t;
            if (first || s_exp[i] == 255) atomicAdd(&s_hist[s_bkt4[j][i]], 1u);
        }
        __syncthreads();

        const unsigned int h0 = s_hist[4 * t], h1 = s_hist[4 * t + 1];
        const unsigned int h2 = s_hist[4 * t + 2], h3 = s_hist[4 * t + 3];
        const unsigned int lsum = h0 + h1 + h2 + h3;
        unsigned int sfx = lsum;
#pragma unroll
        for (int off = 1; off < 64; off <<= 1) {
            const unsigned int vv = __shfl_down(sfx, off, 64);
            if (lane + off < 64) sfx += vv;
        }
        if (lane == 0) s_wsum[wv] = sfx;
        __syncthreads();
        if (t < 16) {
            unsigned int acc = 0;
            for (int w2 = t + 1; w2 < 16; ++w2) acc += s_wsum[w2];
            s_wsum[16 + t] = acc;
        }
        __syncthreads();
        {
            unsigned int run = (sfx - lsum) + s_wsum[16 + wv];
            const unsigned int hh[4] = {h0, h1, h2, h3};
#pragma unroll
            for (int bi = 3; bi >= 0; --bi) {
                const unsigned int h = hh[bi];
                if (run < (unsigned)kk && run + h >= (unsigned)kk) {
                    s_sel[0] = (unsigned)(4 * t + bi);
                    s_sel[1] = (unsigned)kk - run;
                }
                run += h;
            }
        }
        __syncthreads();
        const int Bstar = (int)s_sel[0];
        const unsigned int rem = s_sel[1];

        for (int u = 0; u < ITEMS; ++u) {
            const int i = u * TPB + t;
            if (!first && s_exp[i] != 255) continue;
            const int bk = s_bkt4[j][i];
            if (bk > Bstar) {
                s_exp[i] = (unsigned char)j;
            } else if (bk == Bstar) {
                const unsigned int pos = atomicAdd(&s_sel[2], 1u);
                if (pos < CMAX) { s_cand[pos] = (unsigned int)i; s_ckey[pos] = orderkey(pj[i]); }
            }
        }
        __syncthreads();
        const unsigned int c = s_sel[2];

        if (rem == c) {
            for (int u = 0; u < ITEMS; ++u) {
                const int i = u * TPB + t;
                if ((first || s_exp[i] == 255) && s_bkt4[j][i] == Bstar)
                    s_exp[i] = (unsigned char)j;
            }
            __syncthreads();
        } else if (c <= CMAX) {
            if (wv == 0) {
                unsigned int key = 0u, idx = 0xFFFFFFFFu;
                if (lane < (int)c) { key = s_ckey[lane]; idx = s_cand[lane]; }
                unsigned long long v = ((unsigned long long)(~key) << 32) | idx;
                for (int k2 = 2; k2 <= 64; k2 <<= 1) {
                    for (int jj = k2 >> 1; jj >= 1; jj >>= 1) {
                        const unsigned long long pv = __shfl_xor(v, jj, 64);
                        const bool up = ((lane & k2) == 0);
                        const bool lower = ((lane & jj) == 0);
                        if (lower == up) v = (v < pv) ? v : pv;
                        else             v = (v > pv) ? v : pv;
                    }
                }
                if (lane < (int)rem) {
                    const unsigned int tok = (unsigned int)(v & 0xFFFFFFFFu);
                    s_exp[tok] = (unsigned char)j;
                }
            }
            __syncthreads();
        } else {
            unsigned int prefix = 0, remR = rem;
            for (int shift = 24; shift >= 0; shift -= 8) {
                if (t < 256) s_hist[t] = 0;
                __syncthreads();
                for (int u = 0; u < ITEMS; ++u) {
                    const int i = t * ITEMS + u;
                    if (s_exp[i] != 255) continue;
                    const unsigned int key = orderkey(pj[i]);
                    if (shift == 24 || (key >> (shift + 8)) == prefix)
                        atomicAdd(&s_hist[(key >> shift) & 255u], 1u);
                }
                __syncthreads();
                if (wv == 0) {
                    const unsigned int g0 = s_hist[4 * lane], g1 = s_hist[4 * lane + 1];
                    const unsigned int g2 = s_hist[4 * lane + 2], g3 = s_hist[4 * lane + 3];
                    const unsigned int ls = g0 + g1 + g2 + g3;
                    unsigned int sx = ls;
#pragma unroll
                    for (int off = 1; off < 64; off <<= 1) {
                        const unsigned int vv = __shfl_down(sx, off, 64);
                        if (lane + off < 64) sx += vv;
                    }
                    unsigned int rr = sx - ls;
                    const unsigned int gg[4] = {g0, g1, g2, g3};
#pragma unroll
                    for (int bi = 3; bi >= 0; --bi) {
                        const unsigned int h = gg[bi];
                        if (rr < remR && rr + h >= remR) {
                            s_sel[0] = (unsigned)(4 * lane + bi);
                            s_sel[1] = remR - rr;
                        }
                        rr += h;
                    }
                }
                __syncthreads();
                prefix = (prefix << 8) | s_sel[0];
                remR = s_sel[1];
            }
            const unsigned int T = prefix;
            unsigned int local = 0;
            for (int u = 0; u < ITEMS; ++u) {
                const int i = t * ITEMS + u;
                if (s_exp[i] == 255 && orderkey(pj[i]) == T) ++local;
            }
            unsigned int inc = local;
#pragma unroll
            for (int off = 1; off < 64; off <<= 1) {
                const unsigned int vv = __shfl_up(inc, off, 64);
                if (lane >= off) inc += vv;
            }
            if (lane == 63) s_wsum[wv] = inc;
            __syncthreads();
            if (t < 16) {
                unsigned int a2 = 0;
                for (int w2 = 0; w2 < t; ++w2) a2 += s_wsum[w2];
                s_wsum[16 + t] = a2;
            }
            __syncthreads();
            unsigned int taken = (inc - local) + s_wsum[16 + wv];
            for (int u = 0; u < ITEMS; ++u) {
                const int i = t * ITEMS + u;
                if (s_exp[i] != 255) continue;
                const unsigned int key = orderkey(pj[i]);
                if (key > T) {
                    s_exp[i] = (unsigned char)j;
                } else if (key == T) {
                    if (taken < remR) s_exp[i] = (unsigned char)j;
                    ++taken;
                }
            }
            __syncthreads();
        }
        nun -= kk;
    }

    float* out_mask = out;
    float* out_p = out + (size_t)BN;
    for (int u = 0; u < ITEMS; ++u) {
        const int i = u * TPB + t;
        int e = s_exp[i];
        if (e == 255) e = 0;
        out_mask[(size_t)b * N + i] = (float)e;
        out_p[(size_t)b * N + i] = probs_t[((size_t)b * E + e) * N + i];
    }
}

}  // namespace

extern "C" void kernel_launch(void* const* d_in, const int* in_sizes, int n_in,
                              void* d_out, int out_size, void* d_ws, size_t ws_size,
                              hipStream_t stream) {
    const float* x = (const float*)d_in[0];     // [B, N, D]
    const float* W = (const float*)d_in[1];     // [E, D]
    const float* bias = (const float*)d_in[2];  // [E]
    float* out = (float*)d_out;                 // [2*B*N] floats
    float* probs_t = (float*)d_ws;              // [B, E, N] fp32, 1 MB

    probs_kernel<<<BN / 64, 256, 0, stream>>>(x, W, bias, probs_t);
    route_kernel<<<B, 1024, 0, stream>>>(probs_t, out);
}